// Round 16
// baseline (66.198 us; speedup 1.0000x reference)
//
#include <hip/hip_runtime.h>

#define D_MODEL 1024
#define HDIM    64
#define BATCH   8
#define SEQ     2048
#define BT      (BATCH*SEQ)
#define NCAT    192
#define BM      32
#define BK      64
#define NSTEP   16                       // 1024/64
#define WFRAG   512                      // shorts per frag: 64 lanes x 8
#define WSTEP32 (12*WFRAG)               // 12 hi frags per 32-k step

typedef __attribute__((ext_vector_type(8))) short s8v;
typedef __attribute__((ext_vector_type(4))) float f4;

__device__ __forceinline__ unsigned short f2bf(float f){
    unsigned u = __builtin_bit_cast(unsigned, f);
    u += 0x7fffu + ((u >> 16) & 1u);
    return (unsigned short)(u >> 16);
}
__device__ __forceinline__ float bf2f(unsigned short h){
    unsigned u = ((unsigned)h) << 16;
    return __builtin_bit_cast(float, u);
}
__device__ __forceinline__ f4 MFMA(s8v a, s8v b, f4 c){
    return __builtin_amdgcn_mfma_f32_16x16x32_bf16(a, b, c, 0, 0, 0);
}

// ---- kernel 1: W -> fragment-packed Wt (hi only) ----
// wtP: [k32-step t1][frag nb(12)][lane(64)][e(8)] shorts; frag = contiguous 1KB.
__global__ void prep_w_kernel(const float* __restrict__ wq, const float* __restrict__ wk,
                              const float* __restrict__ wv,
                              short* __restrict__ wtP){
    int ncat = blockIdx.x;
    const float* w = (ncat < 64) ? wq : ((ncat < 128) ? wk : wv);
    int n  = ncat & 63;
    int nb = ncat >> 4, ln = ncat & 15;
    for (int k = threadIdx.x; k < D_MODEL; k += blockDim.x){
        float f = w[k*HDIM + n];
        int t1 = k >> 5, g = (k >> 3) & 3, e = k & 7;
        wtP[(size_t)t1*WSTEP32 + (size_t)nb*WFRAG + ((g*16 + ln) << 3) + e]
            = (short)f2bf(f);
    }
}

// ---- kernel 2: fused QKV projection — BM=32/BK=64, 2 blocks/CU, counted vmcnt ----
// 512 blocks x 8 waves (2 barrier domains/CU, 4 waves/SIMD). Wave tile 16x48.
// X: fp32 -> LDS via global_load_lds, 4 buffers (32 KB), 2 steps ahead,
//    slot-XOR swizzle (slot' = (s&8)|((s&7)^(row&7)); read applies same XOR).
// W: hi-only frags, direct global->reg, 2-step A/B double buffer.
// Ledger (per wave): per step issue [6x W(t+2), 1x X(t+2)] -> top-of-step
// outstanding = W(t),X(t),W(t+1),X(t+1) = 14 -> vmcnt(7) retires W(t)+X(t);
// final step drains vmcnt(0). Numerics identical to round 15.
__global__ __launch_bounds__(512, 4) void proj_kernel(
        const float* __restrict__ x,
        const short* __restrict__ wtP,
        short* __restrict__ q, short* __restrict__ k,
        short* __restrict__ vt){
    __shared__ __align__(16) float xs[4][BM][64];   // 32 KB
    int tid = threadIdx.x;
    int wid = tid >> 6, lane = tid & 63, g = lane >> 4, ln = lane & 15;
    int wm = wid >> 2, wn = wid & 3;   // wave: rows wm*16..+15, cols wn*48..+47
    int m0 = blockIdx.x * BM;

    // gload: wave wid stages rows wid*4 .. wid*4+3; lane l -> row wid*4+(l>>4),
    // 16B-slot l&15; source col-slot pre-swizzled (involution).
    int srow = wid*4 + (lane >> 4);
    int sl   = lane & 15;
    int sswz = (sl & 8) | ((sl & 7) ^ (srow & 7));
    const float* xsrc = x + (size_t)(m0 + srow)*D_MODEL + sswz*4;
    const short* wb   = wtP + (size_t)(wn*3)*WFRAG + (size_t)lane*8;

    f4 acc[3];
#pragma unroll
    for (int i = 0; i < 3; i++) acc[i] = (f4){0.f,0.f,0.f,0.f};

    s8v wA0, wA1, wA2, wA3, wA4, wA5;
    s8v wB0, wB1, wB2, wB3, wB4, wB5;

#define GLOADX(T) { \
    __builtin_amdgcn_global_load_lds(xsrc + (size_t)(T)*BK, \
                                     &xs[(T) & 3][wid*4][0], 16, 0, 0); }

#define LOADW(P, T) { \
    const short* wp = wb + (size_t)(2*(T))*WSTEP32; \
    w##P##0 = *(const s8v*)(wp); \
    w##P##1 = *(const s8v*)(wp + WFRAG); \
    w##P##2 = *(const s8v*)(wp + 2*WFRAG); \
    w##P##3 = *(const s8v*)(wp + WSTEP32); \
    w##P##4 = *(const s8v*)(wp + WSTEP32 + WFRAG); \
    w##P##5 = *(const s8v*)(wp + WSTEP32 + 2*WFRAG); }

#define CVT8(DST, VA, VB) { \
    DST[0] = (short)f2bf(VA.x); DST[1] = (short)f2bf(VA.y); \
    DST[2] = (short)f2bf(VA.z); DST[3] = (short)f2bf(VA.w); \
    DST[4] = (short)f2bf(VB.x); DST[5] = (short)f2bf(VB.y); \
    DST[6] = (short)f2bf(VB.z); DST[7] = (short)f2bf(VB.w); }

// One k-step (two 16x16x32 k-subtiles). vmcnt(VM) then barrier: each wave
// waits its own X(T) slice; the barrier publishes all 8 slices.
#define STEP(P, T, VM) { \
    asm volatile("s_waitcnt vmcnt(" #VM ")" ::: "memory"); \
    __builtin_amdgcn_s_barrier(); \
    __builtin_amdgcn_sched_barrier(0); \
    int bq = (T) & 3, r = wm*16 + ln, r7 = ln & 7; \
    float4 xa = *(const float4*)&xs[bq][r][(((2*g)   ^ r7)) << 2]; \
    float4 xb = *(const float4*)&xs[bq][r][(((2*g+1) ^ r7)) << 2]; \
    float4 xc = *(const float4*)&xs[bq][r][((8 | ((2*g)   ^ r7))) << 2]; \
    float4 xd = *(const float4*)&xs[bq][r][((8 | ((2*g+1) ^ r7))) << 2]; \
    s8v A0, A1; \
    CVT8(A0, xa, xb) \
    CVT8(A1, xc, xd) \
    acc[0] = MFMA(A0, w##P##0, acc[0]); \
    acc[1] = MFMA(A0, w##P##1, acc[1]); \
    acc[2] = MFMA(A0, w##P##2, acc[2]); \
    acc[0] = MFMA(A1, w##P##3, acc[0]); \
    acc[1] = MFMA(A1, w##P##4, acc[1]); \
    acc[2] = MFMA(A1, w##P##5, acc[2]); \
    __builtin_amdgcn_sched_barrier(0); \
    if ((T) + 2 < NSTEP) LOADW(P, (T) + 2) \
    __builtin_amdgcn_sched_barrier(0); \
    if ((T) + 2 < NSTEP) GLOADX((T) + 2) \
    __builtin_amdgcn_sched_barrier(0); \
}

    // prologue — vmcnt ledger order: W0, X0, W1, X1  (7 per step-pair)
    LOADW(A, 0)
    __builtin_amdgcn_sched_barrier(0);
    GLOADX(0)
    __builtin_amdgcn_sched_barrier(0);
    LOADW(B, 1)
    __builtin_amdgcn_sched_barrier(0);
    GLOADX(1)
    __builtin_amdgcn_sched_barrier(0);

    for (int t = 0; t < 14; t += 2){
        STEP(A, t,     7)
        STEP(B, t + 1, 7)
    }
    STEP(A, 14, 7)
    STEP(B, 15, 0)
#undef GLOADX
#undef LOADW
#undef CVT8
#undef STEP

    // epilogue: q,k,v single bf16 (v transposed [B][64][T])
#pragma unroll
    for (int nb = 0; nb < 3; nb++){
        int ncat = wn*48 + nb*16 + ln;
        int mat = ncat >> 6, h = ncat & 63;
#pragma unroll
        for (int r = 0; r < 4; r++){
            size_t trow = (size_t)m0 + wm*16 + g*4 + r;
            float v = acc[nb][r];
            unsigned short hh = f2bf(v);
            if (mat == 0){
                q[trow*HDIM + h] = (short)hh;
            } else if (mat == 1){
                k[trow*HDIM + h] = (short)hh;
            } else {
                size_t bb = trow >> 11, t2 = trow & 2047;
                vt[((bb*HDIM + h) << 11) + t2] = (short)hh;
            }
        }
    }
}

// ---- kernel 3: causal flash attention, in-block KV-split, KVBLK=64 ----
// Single-bf16 Q/K; wave w owns KV tiles w, w+4, ...; partials merged in LDS
// at block end (exact algebra). qi swizzle balances per-CU work.
__global__ __launch_bounds__(256, 5) void attn_kernel(
        const short* __restrict__ qg, const short* __restrict__ kg,
        const short* __restrict__ vt, float* __restrict__ out){
    __shared__ unsigned short plds[4][16][112];
    __shared__ float olds[4][16][65];
    __shared__ float mlds[4][16], llds[4][16];
    const float SC = 0.125f * 1.44269504088896340736f;  // 1/sqrt(64) * log2(e)
    int tid = threadIdx.x;
    int w = tid >> 6, lane = tid & 63, g = lane >> 4, ln = lane & 15;
    int b = blockIdx.y;
    int qi = ((blockIdx.y >> 1) & 1) ? (int)(gridDim.x - 1 - blockIdx.x) : (int)blockIdx.x;
    int tq = qi * 16;

    size_t qoff = ((size_t)b*SEQ + tq + ln) * HDIM + g*8;
    s8v q0 = *(const s8v*)(qg + qoff);
    s8v q1 = *(const s8v*)(qg + qoff + 32);

    f4 o0 = {0.f,0.f,0.f,0.f}, o1 = o0, o2 = o0, o3 = o0;
    float m[4], lsum[4];
#pragma unroll
    for (int r = 0; r < 4; r++){ m[r] = -__builtin_inff(); lsum[r] = 0.f; }

    int ntiles = (tq + 79) >> 6;   // ceil((tq+16)/64)
    for (int ti = w; ti < ntiles; ti += 4){
        int s0 = ti << 6;
        size_t kbase = ((size_t)b*SEQ + s0 + ln) * HDIM + g*8;
        f4 z0, z1, z2, z3;
#define QK_SUBTILE(ZJ, J) { \
        const short* kp = kg + kbase + (J)*16*HDIM; \
        s8v k0 = *(const s8v*)(kp); \
        s8v k1 = *(const s8v*)(kp + 32); \
        f4 s = {0.f,0.f,0.f,0.f}; \
        s = MFMA(q0, k0, s); s = MFMA(q1, k1, s); \
        ZJ[0] = s[0]*SC; ZJ[1] = s[1]*SC; ZJ[2] = s[2]*SC; ZJ[3] = s[3]*SC; }
        QK_SUBTILE(z0, 0)
        QK_SUBTILE(z1, 1)
        QK_SUBTILE(z2, 2)
        QK_SUBTILE(z3, 3)
#undef QK_SUBTILE
        if (s0 + 63 > tq){   // causal mask (near-diagonal tiles only)
#pragma unroll
            for (int r = 0; r < 4; r++){
                int t = tq + g*4 + r;
                if (s0      + ln > t) z0[r] = -__builtin_inff();
                if (s0 + 16 + ln > t) z1[r] = -__builtin_inff();
                if (s0 + 32 + ln > t) z2[r] = -__builtin_inff();
                if (s0 + 48 + ln > t) z3[r] = -__builtin_inff();
            }
        }
        float al[4];
#pragma unroll
        for (int r = 0; r < 4; r++){
            float v = fmaxf(fmaxf(z0[r], z1[r]), fmaxf(z2[r], z3[r]));
            v = fmaxf(v, __shfl_xor(v, 1));
            v = fmaxf(v, __shfl_xor(v, 2));
            v = fmaxf(v, __shfl_xor(v, 4));
            v = fmaxf(v, __shfl_xor(v, 8));
            float mn = fmaxf(m[r], v);
            al[r] = __builtin_amdgcn_exp2f(m[r] - mn);
            float p0 = __builtin_amdgcn_exp2f(z0[r] - mn);
            float p1 = __builtin_amdgcn_exp2f(z1[r] - mn);
            float p2 = __builtin_amdgcn_exp2f(z2[r] - mn);
            float p3 = __builtin_amdgcn_exp2f(z3[r] - mn);
            lsum[r] = lsum[r]*al[r] + ((p0 + p1) + (p2 + p3));  // lane-partial
            m[r] = mn;
            int row = g*4 + r;
            plds[w][row][ln]      = f2bf(p0);
            plds[w][row][ln + 16] = f2bf(p1);
            plds[w][row][ln + 32] = f2bf(p2);
            plds[w][row][ln + 48] = f2bf(p3);
        }
#pragma unroll
        for (int r = 0; r < 4; r++){
            o0[r] *= al[r]; o1[r] *= al[r]; o2[r] *= al[r]; o3[r] *= al[r];
        }
        asm volatile("s_waitcnt lgkmcnt(0)" ::: "memory");  // cross-lane P write->read
        __builtin_amdgcn_sched_barrier(0);
        s8v pa0 = *(const s8v*)&plds[w][ln][g*8];
        s8v pa1 = *(const s8v*)&plds[w][ln][32 + g*8];
        size_t voff = ((size_t)b*HDIM + ln) * SEQ + s0 + g*8;
        s8v v00 = *(const s8v*)(vt + voff);
        s8v v01 = *(const s8v*)(vt + voff + 32);
        s8v v10 = *(const s8v*)(vt + voff + 16*SEQ);
        s8v v11 = *(const s8v*)(vt + voff + 16*SEQ + 32);
        s8v v20 = *(const s8v*)(vt + voff + 32*SEQ);
        s8v v21 = *(const s8v*)(vt + voff + 32*SEQ + 32);
        s8v v30 = *(const s8v*)(vt + voff + 48*SEQ);
        s8v v31 = *(const s8v*)(vt + voff + 48*SEQ + 32);
        o0 = MFMA(pa0, v00, o0); o0 = MFMA(pa1, v01, o0);
        o1 = MFMA(pa0, v10, o1); o1 = MFMA(pa1, v11, o1);
        o2 = MFMA(pa0, v20, o2); o2 = MFMA(pa1, v21, o2);
        o3 = MFMA(pa0, v30, o3); o3 = MFMA(pa1, v31, o3);
    }

    // deferred l-sum reduce (off the per-tile critical path)
#pragma unroll
    for (int r = 0; r < 4; r++){
        float s = lsum[r];
        s += __shfl_xor(s, 1);
        s += __shfl_xor(s, 2);
        s += __shfl_xor(s, 4);
        s += __shfl_xor(s, 8);
        lsum[r] = s;
    }

    // ---- write per-wave partials to LDS ----
#pragma unroll
    for (int r = 0; r < 4; r++){
        int row = g*4 + r;
        olds[w][row][ln]      = o0[r];
        olds[w][row][ln + 16] = o1[r];
        olds[w][row][ln + 32] = o2[r];
        olds[w][row][ln + 48] = o3[r];
        if (ln == 0){ mlds[w][row] = m[r]; llds[w][row] = lsum[r]; }
    }
    __syncthreads();

    // ---- combine 4 partials (exact online-softmax merge), coalesced store ----
    {
        int row = tid >> 4;          // 0..15
        int hb  = tid & 15;          // 0..15
        float m0 = mlds[0][row], m1 = mlds[1][row], m2 = mlds[2][row], m3 = mlds[3][row];
        float M = fmaxf(fmaxf(m0, m1), fmaxf(m2, m3));   // finite: wave 0 always has tile 0
        float w0 = __builtin_amdgcn_exp2f(m0 - M);
        float w1 = __builtin_amdgcn_exp2f(m1 - M);
        float w2 = __builtin_amdgcn_exp2f(m2 - M);
        float w3 = __builtin_amdgcn_exp2f(m3 - M);
        float L = llds[0][row]*w0 + llds[1][row]*w1 + llds[2][row]*w2 + llds[3][row]*w3;
        float inv = 1.0f / L;
        size_t obase = ((size_t)b*SEQ + tq + row) * HDIM + hb;
#pragma unroll
        for (int j = 0; j < 4; j++){
            int h = hb + 16*j;
            float acc = olds[0][row][h]*w0 + olds[1][row][h]*w1
                      + olds[2][row][h]*w2 + olds[3][row][h]*w3;
            out[obase + 16*j] = acc * inv;
        }
    }
}

extern "C" void kernel_launch(void* const* d_in, const int* in_sizes, int n_in,
                              void* d_out, int out_size, void* d_ws, size_t ws_size,
                              hipStream_t stream) {
    (void)in_sizes; (void)n_in; (void)out_size; (void)ws_size;
    const float* x  = (const float*)d_in[0];
    const float* wq = (const float*)d_in[1];
    const float* wk = (const float*)d_in[2];
    const float* wv = (const float*)d_in[3];
    float* out = (float*)d_out;

    short* ws  = (short*)d_ws;               // ~6.4 MB total workspace
    short* wtP = ws;                          // packed W hi-only: 384 KB
    short* q   = wtP + (size_t)32*WSTEP32;
    short* k   = q + (size_t)BT*HDIM;
    short* vt  = k + (size_t)BT*HDIM;

    prep_w_kernel<<<NCAT, 256, 0, stream>>>(wq, wk, wv, wtP);
    proj_kernel<<<BT/BM, 512, 0, stream>>>(x, wtP, q, k, vt);
    attn_kernel<<<dim3(SEQ/16, BATCH), 256, 0, stream>>>(q, k, vt, out);
}

// Round 17
// 60.159 us; speedup vs baseline: 1.1004x; 1.1004x over previous
//
#include <hip/hip_runtime.h>

#define D_MODEL 1024
#define HDIM    64
#define BATCH   8
#define SEQ     2048
#define BT      (BATCH*SEQ)
#define NCAT    192
#define BM      64
#define BK      64
#define NSTEP   16                       // 1024/64
#define WFRAG   512                      // shorts per frag: 64 lanes x 8
#define WSTEP32 (12*WFRAG)               // 12 hi frags per 32-k step

typedef __attribute__((ext_vector_type(8))) short s8v;
typedef __attribute__((ext_vector_type(4))) float f4;

__device__ __forceinline__ unsigned short f2bf(float f){
    unsigned u = __builtin_bit_cast(unsigned, f);
    u += 0x7fffu + ((u >> 16) & 1u);
    return (unsigned short)(u >> 16);
}
__device__ __forceinline__ float bf2f(unsigned short h){
    unsigned u = ((unsigned)h) << 16;
    return __builtin_bit_cast(float, u);
}
__device__ __forceinline__ f4 MFMA(s8v a, s8v b, f4 c){
    return __builtin_amdgcn_mfma_f32_16x16x32_bf16(a, b, c, 0, 0, 0);
}

// ---- kernel 1: W -> fragment-packed Wt (hi only) ----
// wtP: [k32-step t1][frag nb(12)][lane(64)][e(8)] shorts; frag = contiguous 1KB.
__global__ void prep_w_kernel(const float* __restrict__ wq, const float* __restrict__ wk,
                              const float* __restrict__ wv,
                              short* __restrict__ wtP){
    int ncat = blockIdx.x;
    const float* w = (ncat < 64) ? wq : ((ncat < 128) ? wk : wv);
    int n  = ncat & 63;
    int nb = ncat >> 4, ln = ncat & 15;
    for (int k = threadIdx.x; k < D_MODEL; k += blockDim.x){
        float f = w[k*HDIM + n];
        int t1 = k >> 5, g = (k >> 3) & 3, e = k & 7;
        wtP[(size_t)t1*WSTEP32 + (size_t)nb*WFRAG + ((g*16 + ln) << 3) + e]
            = (short)f2bf(f);
    }
}

// ---- kernel 2: fused QKV projection — W-dedup via LDS, 16 waves, counted vmcnt ----
// 256 blocks x 1024 thr (1 block/CU, 4 waves/SIMD). Wave grid 4x4, tile 16x48.
// Per step the block stages ONCE: W panel 24KB (frag-packed, gload_lds native
// lane*16B fit, triple-buffered t%3) + x 16KB fp32 (swizzled, quad-buffered t&3).
// Waves 0-7 stage (3 W frags + 2 x-row gloads = 5 VMEM/step); waves 8-15 issue
// none and pass the per-wave vmcnt trivially. Ledger: issue batch(t+2) during
// step t -> top-of-step vmcnt(5) retires batch(t); last step vmcnt(0).
__global__ __launch_bounds__(1024) void proj_kernel(
        const float* __restrict__ x,
        const short* __restrict__ wtP,
        short* __restrict__ q, short* __restrict__ k,
        short* __restrict__ vt){
    __shared__ __align__(16) float xs[4][BM][64];        // 64 KB
    __shared__ __align__(16) short wlds[3][24][64][8];   // 72 KB
    int tid = threadIdx.x;
    int wid = tid >> 6, lane = tid & 63, g = lane >> 4, ln = lane & 15;
    int wm = wid >> 2, wn = wid & 3;   // wave tile: rows wm*16..+15, cols wn*48..+47
    int m0 = blockIdx.x * BM;

    // staging (waves 0-7): x rows (wid&7)*8 .. +7 via 2 gloads; W frags wid*3..+2.
    int rowA = (wid & 7)*8 + (lane >> 4), rowB = rowA + 4;
    int sl   = lane & 15;
    int swzA = (sl & 8) | ((sl & 7) ^ (rowA & 7));
    int swzB = (sl & 8) | ((sl & 7) ^ (rowB & 7));
    const float* xsrcA = x + (size_t)(m0 + rowA)*D_MODEL + swzA*4;
    const float* xsrcB = x + (size_t)(m0 + rowB)*D_MODEL + swzB*4;
    const short* wsrc  = wtP + (size_t)(wid*3)*WFRAG + (size_t)lane*8;

    f4 acc[3];
#pragma unroll
    for (int i = 0; i < 3; i++) acc[i] = (f4){0.f,0.f,0.f,0.f};

#define CVT8(DST, VA, VB) { \
    DST[0] = (short)f2bf(VA.x); DST[1] = (short)f2bf(VA.y); \
    DST[2] = (short)f2bf(VA.z); DST[3] = (short)f2bf(VA.w); \
    DST[4] = (short)f2bf(VB.x); DST[5] = (short)f2bf(VB.y); \
    DST[6] = (short)f2bf(VB.z); DST[7] = (short)f2bf(VB.w); }

// Stage batch T (waves 0-7 only): 3x W frag (1KB each) + 2x x-rows (1KB each).
#define GSTAGE(T) if (wid < 8){ \
    const short* wp = wsrc + (size_t)(2*(T))*WSTEP32; \
    __builtin_amdgcn_global_load_lds(wp,           &wlds[(T)%3][wid*3    ][0][0], 16, 0, 0); \
    __builtin_amdgcn_global_load_lds(wp +   WFRAG, &wlds[(T)%3][wid*3 + 1][0][0], 16, 0, 0); \
    __builtin_amdgcn_global_load_lds(wp + 2*WFRAG, &wlds[(T)%3][wid*3 + 2][0][0], 16, 0, 0); \
    __builtin_amdgcn_global_load_lds(xsrcA + (size_t)(T)*BK, &xs[(T)&3][(wid&7)*8    ][0], 16, 0, 0); \
    __builtin_amdgcn_global_load_lds(xsrcB + (size_t)(T)*BK, &xs[(T)&3][(wid&7)*8 + 4][0], 16, 0, 0); }

// One k-step (BK=64 = two 16x16x32 k-subtiles).
#define STEP(T, VM) { \
    asm volatile("s_waitcnt vmcnt(" #VM ")" ::: "memory"); \
    __builtin_amdgcn_s_barrier(); \
    __builtin_amdgcn_sched_barrier(0); \
    int bq = (T) & 3, wq = (T) % 3, r7 = ln & 7; \
    int r = wm*16 + ln; \
    float4 xa = *(const float4*)&xs[bq][r][(((2*g)   ^ r7)) << 2]; \
    float4 xb = *(const float4*)&xs[bq][r][(((2*g+1) ^ r7)) << 2]; \
    float4 xc = *(const float4*)&xs[bq][r][((8 | ((2*g)   ^ r7))) << 2]; \
    float4 xd = *(const float4*)&xs[bq][r][((8 | ((2*g+1) ^ r7))) << 2]; \
    s8v A0, A1; \
    CVT8(A0, xa, xb) \
    CVT8(A1, xc, xd) \
    s8v B00 = *(const s8v*)&wlds[wq][     wn*3    ][lane][0]; \
    s8v B01 = *(const s8v*)&wlds[wq][     wn*3 + 1][lane][0]; \
    s8v B02 = *(const s8v*)&wlds[wq][     wn*3 + 2][lane][0]; \
    s8v B10 = *(const s8v*)&wlds[wq][12 + wn*3    ][lane][0]; \
    s8v B11 = *(const s8v*)&wlds[wq][12 + wn*3 + 1][lane][0]; \
    s8v B12 = *(const s8v*)&wlds[wq][12 + wn*3 + 2][lane][0]; \
    acc[0] = MFMA(A0, B00, acc[0]); \
    acc[1] = MFMA(A0, B01, acc[1]); \
    acc[2] = MFMA(A0, B02, acc[2]); \
    acc[0] = MFMA(A1, B10, acc[0]); \
    acc[1] = MFMA(A1, B11, acc[1]); \
    acc[2] = MFMA(A1, B12, acc[2]); \
    __builtin_amdgcn_sched_barrier(0); \
    if ((T) + 2 < NSTEP) GSTAGE((T) + 2) \
    __builtin_amdgcn_sched_barrier(0); \
}

    // prologue: batches 0 and 1 in flight (10 VMEM per staging wave)
    GSTAGE(0)
    __builtin_amdgcn_sched_barrier(0);
    GSTAGE(1)
    __builtin_amdgcn_sched_barrier(0);

    for (int t = 0; t < NSTEP - 1; ++t){
        STEP(t, 5)
    }
    STEP(15, 0)
#undef GSTAGE
#undef CVT8
#undef STEP

    // epilogue: q,k,v single bf16 (v transposed [B][64][T])
#pragma unroll
    for (int nb = 0; nb < 3; nb++){
        int ncat = wn*48 + nb*16 + ln;
        int mat = ncat >> 6, h = ncat & 63;
#pragma unroll
        for (int r = 0; r < 4; r++){
            size_t trow = (size_t)m0 + wm*16 + g*4 + r;
            float v = acc[nb][r];
            unsigned short hh = f2bf(v);
            if (mat == 0){
                q[trow*HDIM + h] = (short)hh;
            } else if (mat == 1){
                k[trow*HDIM + h] = (short)hh;
            } else {
                size_t bb = trow >> 11, t2 = trow & 2047;
                vt[((bb*HDIM + h) << 11) + t2] = (short)hh;
            }
        }
    }
}

// ---- kernel 3: causal flash attention, in-block KV-split, KVBLK=64 ----
// Single-bf16 Q/K; wave w owns KV tiles w, w+4, ...; partials merged in LDS
// at block end (exact algebra). qi swizzle balances per-CU work.
__global__ __launch_bounds__(256, 5) void attn_kernel(
        const short* __restrict__ qg, const short* __restrict__ kg,
        const short* __restrict__ vt, float* __restrict__ out){
    __shared__ unsigned short plds[4][16][112];
    __shared__ float olds[4][16][65];
    __shared__ float mlds[4][16], llds[4][16];
    const float SC = 0.125f * 1.44269504088896340736f;  // 1/sqrt(64) * log2(e)
    int tid = threadIdx.x;
    int w = tid >> 6, lane = tid & 63, g = lane >> 4, ln = lane & 15;
    int b = blockIdx.y;
    int qi = ((blockIdx.y >> 1) & 1) ? (int)(gridDim.x - 1 - blockIdx.x) : (int)blockIdx.x;
    int tq = qi * 16;

    size_t qoff = ((size_t)b*SEQ + tq + ln) * HDIM + g*8;
    s8v q0 = *(const s8v*)(qg + qoff);
    s8v q1 = *(const s8v*)(qg + qoff + 32);

    f4 o0 = {0.f,0.f,0.f,0.f}, o1 = o0, o2 = o0, o3 = o0;
    float m[4], lsum[4];
#pragma unroll
    for (int r = 0; r < 4; r++){ m[r] = -__builtin_inff(); lsum[r] = 0.f; }

    int ntiles = (tq + 79) >> 6;   // ceil((tq+16)/64)
    for (int ti = w; ti < ntiles; ti += 4){
        int s0 = ti << 6;
        size_t kbase = ((size_t)b*SEQ + s0 + ln) * HDIM + g*8;
        f4 z0, z1, z2, z3;
#define QK_SUBTILE(ZJ, J) { \
        const short* kp = kg + kbase + (J)*16*HDIM; \
        s8v k0 = *(const s8v*)(kp); \
        s8v k1 = *(const s8v*)(kp + 32); \
        f4 s = {0.f,0.f,0.f,0.f}; \
        s = MFMA(q0, k0, s); s = MFMA(q1, k1, s); \
        ZJ[0] = s[0]*SC; ZJ[1] = s[1]*SC; ZJ[2] = s[2]*SC; ZJ[3] = s[3]*SC; }
        QK_SUBTILE(z0, 0)
        QK_SUBTILE(z1, 1)
        QK_SUBTILE(z2, 2)
        QK_SUBTILE(z3, 3)
#undef QK_SUBTILE
        if (s0 + 63 > tq){   // causal mask (near-diagonal tiles only)
#pragma unroll
            for (int r = 0; r < 4; r++){
                int t = tq + g*4 + r;
                if (s0      + ln > t) z0[r] = -__builtin_inff();
                if (s0 + 16 + ln > t) z1[r] = -__builtin_inff();
                if (s0 + 32 + ln > t) z2[r] = -__builtin_inff();
                if (s0 + 48 + ln > t) z3[r] = -__builtin_inff();
            }
        }
        float al[4];
#pragma unroll
        for (int r = 0; r < 4; r++){
            float v = fmaxf(fmaxf(z0[r], z1[r]), fmaxf(z2[r], z3[r]));
            v = fmaxf(v, __shfl_xor(v, 1));
            v = fmaxf(v, __shfl_xor(v, 2));
            v = fmaxf(v, __shfl_xor(v, 4));
            v = fmaxf(v, __shfl_xor(v, 8));
            float mn = fmaxf(m[r], v);
            al[r] = __builtin_amdgcn_exp2f(m[r] - mn);
            float p0 = __builtin_amdgcn_exp2f(z0[r] - mn);
            float p1 = __builtin_amdgcn_exp2f(z1[r] - mn);
            float p2 = __builtin_amdgcn_exp2f(z2[r] - mn);
            float p3 = __builtin_amdgcn_exp2f(z3[r] - mn);
            lsum[r] = lsum[r]*al[r] + ((p0 + p1) + (p2 + p3));  // lane-partial
            m[r] = mn;
            int row = g*4 + r;
            plds[w][row][ln]      = f2bf(p0);
            plds[w][row][ln + 16] = f2bf(p1);
            plds[w][row][ln + 32] = f2bf(p2);
            plds[w][row][ln + 48] = f2bf(p3);
        }
#pragma unroll
        for (int r = 0; r < 4; r++){
            o0[r] *= al[r]; o1[r] *= al[r]; o2[r] *= al[r]; o3[r] *= al[r];
        }
        asm volatile("s_waitcnt lgkmcnt(0)" ::: "memory");  // cross-lane P write->read
        __builtin_amdgcn_sched_barrier(0);
        s8v pa0 = *(const s8v*)&plds[w][ln][g*8];
        s8v pa1 = *(const s8v*)&plds[w][ln][32 + g*8];
        size_t voff = ((size_t)b*HDIM + ln) * SEQ + s0 + g*8;
        s8v v00 = *(const s8v*)(vt + voff);
        s8v v01 = *(const s8v*)(vt + voff + 32);
        s8v v10 = *(const s8v*)(vt + voff + 16*SEQ);
        s8v v11 = *(const s8v*)(vt + voff + 16*SEQ + 32);
        s8v v20 = *(const s8v*)(vt + voff + 32*SEQ);
        s8v v21 = *(const s8v*)(vt + voff + 32*SEQ + 32);
        s8v v30 = *(const s8v*)(vt + voff + 48*SEQ);
        s8v v31 = *(const s8v*)(vt + voff + 48*SEQ + 32);
        o0 = MFMA(pa0, v00, o0); o0 = MFMA(pa1, v01, o0);
        o1 = MFMA(pa0, v10, o1); o1 = MFMA(pa1, v11, o1);
        o2 = MFMA(pa0, v20, o2); o2 = MFMA(pa1, v21, o2);
        o3 = MFMA(pa0, v30, o3); o3 = MFMA(pa1, v31, o3);
    }

    // deferred l-sum reduce (off the per-tile critical path)
#pragma unroll
    for (int r = 0; r < 4; r++){
        float s = lsum[r];
        s += __shfl_xor(s, 1);
        s += __shfl_xor(s, 2);
        s += __shfl_xor(s, 4);
        s += __shfl_xor(s, 8);
        lsum[r] = s;
    }

    // ---- write per-wave partials to LDS ----
#pragma unroll
    for (int r = 0; r < 4; r++){
        int row = g*4 + r;
        olds[w][row][ln]      = o0[r];
        olds[w][row][ln + 16] = o1[r];
        olds[w][row][ln + 32] = o2[r];
        olds[w][row][ln + 48] = o3[r];
        if (ln == 0){ mlds[w][row] = m[r]; llds[w][row] = lsum[r]; }
    }
    __syncthreads();

    // ---- combine 4 partials (exact online-softmax merge), coalesced store ----
    {
        int row = tid >> 4;          // 0..15
        int hb  = tid & 15;          // 0..15
        float m0 = mlds[0][row], m1 = mlds[1][row], m2 = mlds[2][row], m3 = mlds[3][row];
        float M = fmaxf(fmaxf(m0, m1), fmaxf(m2, m3));   // finite: wave 0 always has tile 0
        float w0 = __builtin_amdgcn_exp2f(m0 - M);
        float w1 = __builtin_amdgcn_exp2f(m1 - M);
        float w2 = __builtin_amdgcn_exp2f(m2 - M);
        float w3 = __builtin_amdgcn_exp2f(m3 - M);
        float L = llds[0][row]*w0 + llds[1][row]*w1 + llds[2][row]*w2 + llds[3][row]*w3;
        float inv = 1.0f / L;
        size_t obase = ((size_t)b*SEQ + tq + row) * HDIM + hb;
#pragma unroll
        for (int j = 0; j < 4; j++){
            int h = hb + 16*j;
            float acc = olds[0][row][h]*w0 + olds[1][row][h]*w1
                      + olds[2][row][h]*w2 + olds[3][row][h]*w3;
            out[obase + 16*j] = acc * inv;
        }
    }
}

extern "C" void kernel_launch(void* const* d_in, const int* in_sizes, int n_in,
                              void* d_out, int out_size, void* d_ws, size_t ws_size,
                              hipStream_t stream) {
    (void)in_sizes; (void)n_in; (void)out_size; (void)ws_size;
    const float* x  = (const float*)d_in[0];
    const float* wq = (const float*)d_in[1];
    const float* wk = (const float*)d_in[2];
    const float* wv = (const float*)d_in[3];
    float* out = (float*)d_out;

    short* ws  = (short*)d_ws;               // ~6.4 MB total workspace
    short* wtP = ws;                          // packed W hi-only: 384 KB
    short* q   = wtP + (size_t)32*WSTEP32;
    short* k   = q + (size_t)BT*HDIM;
    short* vt  = k + (size_t)BT*HDIM;

    prep_w_kernel<<<NCAT, 256, 0, stream>>>(wq, wk, wv, wtP);
    proj_kernel<<<BT/BM, 1024, 0, stream>>>(x, wtP, q, k, vt);
    attn_kernel<<<dim3(SEQ/16, BATCH), 256, 0, stream>>>(q, k, vt, out);
}